// Round 17
// baseline (144.616 us; speedup 1.0000x reference)
//
#include <hip/hip_runtime.h>

#define N_NODES 20000
#define N_EDGES 150000
#define FEAT 64
#define HEADS 8
#define N_RBF 20
#define COLS 1024   // 2 * HEADS * FEAT  (Q block then K block)

#define QK_BYTES  40960000ull                 // 20000*1024*2
#define EF_BYTES  (9375ull * 1024ull)         // tiles * [4][16][8] bf16
 
typedef __attribute__((ext_vector_type(8))) short short8;
typedef __attribute__((ext_vector_type(4))) float f32x4;

union frag_u { int4 i; short8 s; };

__device__ __forceinline__ unsigned short f2bf(float x) {
    unsigned int u = __float_as_uint(x);
    unsigned int r = (u + 0x7FFFu + ((u >> 16) & 1u)) >> 16;
    return (unsigned short)r;
}
__device__ __forceinline__ unsigned int pack2bf(float lo, float hi) {
    return f2bf(lo) | ((unsigned int)f2bf(hi) << 16);
}
__device__ __forceinline__ float fsilu(float x) {
    return x * __builtin_amdgcn_rcpf(1.0f + __expf(-x));
}

// ---------------------------------------------------------------------------
// ef precompute: ONE evaluation per edge (was 16x inside K2).
// Output layout [tile][g][16 edges][8 bf16] so K2's B-frag load is one
// coalesced dwordx4 per lane. Bias column (1.0 at k=20) folded in.
// ---------------------------------------------------------------------------
__global__ __launch_bounds__(256) void ef_k(const float* __restrict__ dist,
                                            unsigned short* __restrict__ effb) {
    int e = blockIdx.x * 256 + threadIdx.x;
    if (e >= N_EDGES) return;
    float d = dist[e];
    float theta = 0.62831853071795864769f * d;   // pi*d/5
    float s1, c1;
    __sincosf(theta, &s1, &c1);
    float env = (d < 5.0f) ? 0.5f * (c1 + 1.0f) : 0.0f;
    float scale = env / d;
    float ef[N_RBF];
    float twoc = 2.0f * c1, sm1 = 0.0f, ss = s1;
#pragma unroll
    for (int r = 0; r < N_RBF; ++r) {
        ef[r] = ss * scale;
        float nx = twoc * ss - sm1;
        sm1 = ss; ss = nx;
    }
    unsigned int w[12];
#pragma unroll
    for (int q = 0; q < 10; ++q) w[q] = pack2bf(ef[2*q], ef[2*q+1]);
    w[10] = 0x3F80u;   // k=20 -> 1.0 (bias), k=21 -> 0
    w[11] = 0u;

    const int tile = e >> 4, idx = e & 15;
    unsigned short* base = effb + (size_t)tile * 512;   // 512 shorts/tile
    *reinterpret_cast<uint4*>(base + 0 * 128 + idx * 8) = make_uint4(w[0], w[1], w[2], w[3]);
    *reinterpret_cast<uint4*>(base + 1 * 128 + idx * 8) = make_uint4(w[4], w[5], w[6], w[7]);
    *reinterpret_cast<uint4*>(base + 2 * 128 + idx * 8) = make_uint4(w[8], w[9], w[10], w[11]);
    *reinterpret_cast<uint4*>(base + 3 * 128 + idx * 8) = make_uint4(0u, 0u, 0u, 0u);
}

// ---------------------------------------------------------------------------
// K1 (MFMA, no LDS, W persistent, PERMUTED store) — unchanged from round 13.
// ---------------------------------------------------------------------------
__global__ __launch_bounds__(256, 4) void qk_project_mfma(
    const float* __restrict__ x,
    const float* __restrict__ Wq, const float* __restrict__ bq,
    const float* __restrict__ Wk, const float* __restrict__ bk,
    unsigned short* __restrict__ qk)
{
    const int tid = threadIdx.x;
    const int lane = tid & 63;
    const int wv = tid >> 6;
    const int l15 = lane & 15;
    const int g = lane >> 4;

    const int colBase = blockIdx.x * 256 + wv * 64;
    const bool isK = colBase >= 512;
    const float* W = isK ? Wk : Wq;
    const float* bias = isK ? bk : bq;
    const int colW = colBase & 511;

    short8 aw[4][2];
#pragma unroll
    for (int c = 0; c < 4; ++c) {
#pragma unroll
        for (int s = 0; s < 2; ++s) {
            const float* p = W + (colW + 16 * c + l15) * 64 + 32 * s + 8 * g;
            float4 v0 = *reinterpret_cast<const float4*>(p);
            float4 v1 = *reinterpret_cast<const float4*>(p + 4);
            frag_u f;
            f.i.x = pack2bf(v0.x, v0.y);
            f.i.y = pack2bf(v0.z, v0.w);
            f.i.z = pack2bf(v1.x, v1.y);
            f.i.w = pack2bf(v1.z, v1.w);
            aw[c][s] = f.s;
        }
    }
    float4 b4[4];
#pragma unroll
    for (int c = 0; c < 4; ++c)
        b4[c] = *reinterpret_cast<const float4*>(bias + colW + 16 * c + 4 * g);

    for (int i = 0; i < 8; ++i) {
        int nt = blockIdx.y * 8 + i;
        if (nt >= N_NODES / 16) break;
        int nodeBase = nt * 16;

        short8 bx[2];
#pragma unroll
        for (int s = 0; s < 2; ++s) {
            const float* p = x + (nodeBase + l15) * 64 + 32 * s + 8 * g;
            float4 v0 = *reinterpret_cast<const float4*>(p);
            float4 v1 = *reinterpret_cast<const float4*>(p + 4);
            frag_u f;
            f.i.x = pack2bf(v0.x, v0.y);
            f.i.y = pack2bf(v0.z, v0.w);
            f.i.z = pack2bf(v1.x, v1.y);
            f.i.w = pack2bf(v1.z, v1.w);
            bx[s] = f.s;
        }

#pragma unroll
        for (int c = 0; c < 4; ++c) {
            f32x4 acc = {0.f, 0.f, 0.f, 0.f};
#pragma unroll
            for (int s = 0; s < 2; ++s)
                acc = __builtin_amdgcn_mfma_f32_16x16x32_bf16(aw[c][s], bx[s], acc, 0, 0, 0);
            ushort4 sv;
            sv.x = f2bf(acc[0] + b4[c].x);
            sv.y = f2bf(acc[1] + b4[c].y);
            sv.z = f2bf(acc[2] + b4[c].z);
            sv.w = f2bf(acc[3] + b4[c].w);
            *reinterpret_cast<ushort4*>(
                qk + (size_t)(nodeBase + l15) * COLS + colBase + g * 16 + c * 4) = sv;
        }
    }
}

// ---------------------------------------------------------------------------
// K2 (MFMA, r13 structure). PRE=1: B-frag loaded from precomputed effb
// (one coalesced dwordx4) instead of 16x-redundant in-lane sincos chain.
// ---------------------------------------------------------------------------
template <int PRE>
__global__ __launch_bounds__(128, 6) void edge_attn(
    const float* __restrict__ dist,
    const int* __restrict__ nbrs,      // [E][2]
    const float* __restrict__ Wdk,     // [8][64][20]
    const float* __restrict__ bdk,     // [8][64]
    const unsigned short* __restrict__ qk,   // [N][1024] bf16, permuted
    const unsigned short* __restrict__ effb, // [tile][4][16][8] bf16 (PRE)
    float* __restrict__ out)           // [E][8]
{
    const int tid = threadIdx.x;
    const int hp = (blockIdx.x & 1) * 2 + (tid >> 6);  // head pair 0..3
    const int h0 = hp * 2;
    const int tg = blockIdx.x >> 1;                     // tile group
    const int lane = tid & 63;
    const int l15 = lane & 15;
    const int g = lane >> 4;

    // ---- A-frags: W_dk rows for this head pair (+bias at k=20), once ----
    short8 aw[8];
#pragma unroll
    for (int m = 0; m < 8; ++m) {
        int R = (h0 + (m >> 2)) * 64 + 16 * (m & 3) + l15;
        float wv[8];
        if (g < 2) {
            const float* p = Wdk + R * 20 + 8 * g;
            float4 v0 = *reinterpret_cast<const float4*>(p);
            float4 v1 = *reinterpret_cast<const float4*>(p + 4);
            wv[0]=v0.x; wv[1]=v0.y; wv[2]=v0.z; wv[3]=v0.w;
            wv[4]=v1.x; wv[5]=v1.y; wv[6]=v1.z; wv[7]=v1.w;
        } else if (g == 2) {
            const float* p = Wdk + R * 20 + 16;
            float4 v0 = *reinterpret_cast<const float4*>(p);
            wv[0]=v0.x; wv[1]=v0.y; wv[2]=v0.z; wv[3]=v0.w;
            wv[4]=bdk[R]; wv[5]=0.0f; wv[6]=0.0f; wv[7]=0.0f;
        } else {
            wv[0]=wv[1]=wv[2]=wv[3]=wv[4]=wv[5]=wv[6]=wv[7]=0.0f;
        }
        frag_u f;
        f.i.x = pack2bf(wv[0], wv[1]);
        f.i.y = pack2bf(wv[2], wv[3]);
        f.i.z = pack2bf(wv[4], wv[5]);
        f.i.w = pack2bf(wv[6], wv[7]);
        aw[m] = f.s;
    }

    const char* qkb = reinterpret_cast<const char*>(qk);

#pragma unroll 1
    for (int i = 0; i < 4; ++i) {
        const int tile = tg * 4 + i;
        if (tile >= N_EDGES / 16) break;     // tiles 0..9374
        const int e = tile * 16 + l15;

        // ---- gathers: 8 x dwordx4 (permuted layout, 32B/lane/head) ----
        int2 nn = *reinterpret_cast<const int2*>(&nbrs[2 * e]);
        const char* bq = qkb + (size_t)nn.x * 2048 + h0 * 128 + 32 * g;
        const char* bk = qkb + (size_t)nn.y * 2048 + 1024 + h0 * 128 + 32 * g;
        uint4 qv[4], kv[4];
        qv[0] = *reinterpret_cast<const uint4*>(bq);
        qv[1] = *reinterpret_cast<const uint4*>(bq + 16);
        qv[2] = *reinterpret_cast<const uint4*>(bq + 128);
        qv[3] = *reinterpret_cast<const uint4*>(bq + 144);
        kv[0] = *reinterpret_cast<const uint4*>(bk);
        kv[1] = *reinterpret_cast<const uint4*>(bk + 16);
        kv[2] = *reinterpret_cast<const uint4*>(bk + 128);
        kv[3] = *reinterpret_cast<const uint4*>(bk + 144);

        unsigned int qr[16], kr[16];         // static indices only
#pragma unroll
        for (int j = 0; j < 4; ++j) {
            qr[4*j+0] = qv[j].x; qr[4*j+1] = qv[j].y;
            qr[4*j+2] = qv[j].z; qr[4*j+3] = qv[j].w;
            kr[4*j+0] = kv[j].x; kr[4*j+1] = kv[j].y;
            kr[4*j+2] = kv[j].z; kr[4*j+3] = kv[j].w;
        }

        // ---- B-frag ----
        frag_u bf_;
        if (PRE) {
            bf_.i = *reinterpret_cast<const int4*>(
                effb + (size_t)tile * 512 + g * 128 + l15 * 8);
        } else {
            float ef[N_RBF];
            float d = dist[e];
            float theta = 0.62831853071795864769f * d;
            float s1, c1;
            __sincosf(theta, &s1, &c1);
            float env = (d < 5.0f) ? 0.5f * (c1 + 1.0f) : 0.0f;
            float scale = env / d;
            float twoc = 2.0f * c1, sm1 = 0.0f, ss = s1;
#pragma unroll
            for (int r = 0; r < N_RBF; ++r) {
                ef[r] = ss * scale;
                float nx = twoc * ss - sm1;
                sm1 = ss; ss = nx;
            }
            float v[8];
#pragma unroll
            for (int j = 0; j < 8; ++j) {
                float a0 = ef[j];
                float a1 = ef[j + 8];
                float a2 = (j + 16 < 20) ? ef[(j + 16 < 20) ? j + 16 : 0]
                                         : (j + 16 == 20 ? 1.0f : 0.0f);
                v[j] = (g == 0) ? a0 : (g == 1) ? a1 : (g == 2) ? a2 : 0.0f;
            }
            bf_.i.x = pack2bf(v[0], v[1]);
            bf_.i.y = pack2bf(v[2], v[3]);
            bf_.i.z = pack2bf(v[4], v[5]);
            bf_.i.w = pack2bf(v[6], v[7]);
        }

        // ---- 8 MFMAs + contraction ----
        float tA = 0.0f, tB = 0.0f;
#pragma unroll
        for (int m = 0; m < 8; ++m) {
            f32x4 z = {0.0f, 0.0f, 0.0f, 0.0f};
            f32x4 acc = __builtin_amdgcn_mfma_f32_16x16x32_bf16(aw[m], bf_.s, z, 0, 0, 0);
            const int hh = m >> 2, t = m & 3;
#pragma unroll
            for (int r2 = 0; r2 < 4; ++r2) {
                const int dw = hh * 8 + t * 2 + (r2 >> 1);
                unsigned int qw = qr[dw];
                unsigned int kw = kr[dw];
                float qf = (r2 & 1) ? __uint_as_float(qw & 0xFFFF0000u)
                                    : __uint_as_float(qw << 16);
                float kf = (r2 & 1) ? __uint_as_float(kw & 0xFFFF0000u)
                                    : __uint_as_float(kw << 16);
                float dk = fsilu(acc[r2]);
                float p = qf * kf;
                if (m < 4) tA = fmaf(p, dk, tA);
                else       tB = fmaf(p, dk, tB);
            }
        }

        // reduce across the 4 lanes sharing this edge
        tA += __shfl_xor(tA, 16);
        tA += __shfl_xor(tA, 32);
        tB += __shfl_xor(tB, 16);
        tB += __shfl_xor(tB, 32);

        if (lane < 16) {
            float2 o = make_float2(fsilu(tA), fsilu(tB));
            *reinterpret_cast<float2*>(out + (size_t)e * 8 + h0) = o;
        }
    }
}

extern "C" void kernel_launch(void* const* d_in, const int* in_sizes, int n_in,
                              void* d_out, int out_size, void* d_ws, size_t ws_size,
                              hipStream_t stream) {
    const float* dist = (const float*)d_in[0];
    const int* nbrs   = (const int*)d_in[1];
    const float* x_i  = (const float*)d_in[2];
    const float* W_q  = (const float*)d_in[3];
    const float* b_q  = (const float*)d_in[4];
    const float* W_k  = (const float*)d_in[5];
    const float* b_k  = (const float*)d_in[6];
    const float* W_dk = (const float*)d_in[7];
    const float* b_dk = (const float*)d_in[8];
    float* out = (float*)d_out;

    char* ws = (char*)d_ws;
    unsigned short* qkbuf = (unsigned short*)ws;
    unsigned short* effb  = (unsigned short*)(ws + QK_BYTES);
    const bool usePre = ws_size >= QK_BYTES + EF_BYTES;

    if (usePre)
        ef_k<<<(N_EDGES + 255) / 256, 256, 0, stream>>>(dist, effb);

    dim3 g1(4, (N_NODES / 16 + 7) / 8);   // 4 col-groups x 157 node-chunks
    qk_project_mfma<<<g1, 256, 0, stream>>>(x_i, W_q, b_q, W_k, b_k, qkbuf);

    const int nTiles = N_EDGES / 16;              // 9375
    const int nb = ((nTiles + 3) / 4) * 2;        // 2344 groups x 2 hp-blocks
    if (usePre)
        edge_attn<1><<<nb, 128, 0, stream>>>(dist, nbrs, W_dk, b_dk, qkbuf, effb, out);
    else
        edge_attn<0><<<nb, 128, 0, stream>>>(dist, nbrs, W_dk, b_dk, qkbuf, effb, out);
}

// Round 18
// 83.694 us; speedup vs baseline: 1.7279x; 1.7279x over previous
//
#include <hip/hip_runtime.h>

#define N_NODES 20000
#define N_EDGES 150000
#define FEAT 64
#define HEADS 8
#define N_RBF 20
#define COLS 1024   // 2 * HEADS * FEAT  (Q block then K block)

typedef __attribute__((ext_vector_type(8))) short short8;
typedef __attribute__((ext_vector_type(4))) float f32x4;

union frag_u { int4 i; short8 s; };

__device__ __forceinline__ unsigned short f2bf(float x) {
    unsigned int u = __float_as_uint(x);
    unsigned int r = (u + 0x7FFFu + ((u >> 16) & 1u)) >> 16;
    return (unsigned short)r;
}
__device__ __forceinline__ unsigned int pack2bf(float lo, float hi) {
    return f2bf(lo) | ((unsigned int)f2bf(hi) << 16);
}
__device__ __forceinline__ float fsilu(float x) {
    return x * __builtin_amdgcn_rcpf(1.0f + __expf(-x));
}

// ---------------------------------------------------------------------------
// K1 (MFMA, no LDS, W persistent, PERMUTED store) — r13 exact.
// Within each head's 64-col block, feature c=16t+4g+r2 stored at p=16g+4t+r2
// so K2's per-lane slice is a contiguous 32B run.
// ---------------------------------------------------------------------------
__global__ __launch_bounds__(256, 4) void qk_project_mfma(
    const float* __restrict__ x,
    const float* __restrict__ Wq, const float* __restrict__ bq,
    const float* __restrict__ Wk, const float* __restrict__ bk,
    unsigned short* __restrict__ qk)
{
    const int tid = threadIdx.x;
    const int lane = tid & 63;
    const int wv = tid >> 6;
    const int l15 = lane & 15;
    const int g = lane >> 4;

    const int colBase = blockIdx.x * 256 + wv * 64;
    const bool isK = colBase >= 512;
    const float* W = isK ? Wk : Wq;
    const float* bias = isK ? bk : bq;
    const int colW = colBase & 511;

    short8 aw[4][2];
#pragma unroll
    for (int c = 0; c < 4; ++c) {
#pragma unroll
        for (int s = 0; s < 2; ++s) {
            const float* p = W + (colW + 16 * c + l15) * 64 + 32 * s + 8 * g;
            float4 v0 = *reinterpret_cast<const float4*>(p);
            float4 v1 = *reinterpret_cast<const float4*>(p + 4);
            frag_u f;
            f.i.x = pack2bf(v0.x, v0.y);
            f.i.y = pack2bf(v0.z, v0.w);
            f.i.z = pack2bf(v1.x, v1.y);
            f.i.w = pack2bf(v1.z, v1.w);
            aw[c][s] = f.s;
        }
    }
    float4 b4[4];
#pragma unroll
    for (int c = 0; c < 4; ++c)
        b4[c] = *reinterpret_cast<const float4*>(bias + colW + 16 * c + 4 * g);

    for (int i = 0; i < 8; ++i) {
        int nt = blockIdx.y * 8 + i;
        if (nt >= N_NODES / 16) break;
        int nodeBase = nt * 16;

        short8 bx[2];
#pragma unroll
        for (int s = 0; s < 2; ++s) {
            const float* p = x + (nodeBase + l15) * 64 + 32 * s + 8 * g;
            float4 v0 = *reinterpret_cast<const float4*>(p);
            float4 v1 = *reinterpret_cast<const float4*>(p + 4);
            frag_u f;
            f.i.x = pack2bf(v0.x, v0.y);
            f.i.y = pack2bf(v0.z, v0.w);
            f.i.z = pack2bf(v1.x, v1.y);
            f.i.w = pack2bf(v1.z, v1.w);
            bx[s] = f.s;
        }

#pragma unroll
        for (int c = 0; c < 4; ++c) {
            f32x4 acc = {0.f, 0.f, 0.f, 0.f};
#pragma unroll
            for (int s = 0; s < 2; ++s)
                acc = __builtin_amdgcn_mfma_f32_16x16x32_bf16(aw[c][s], bx[s], acc, 0, 0, 0);
            ushort4 sv;
            sv.x = f2bf(acc[0] + b4[c].x);
            sv.y = f2bf(acc[1] + b4[c].y);
            sv.z = f2bf(acc[2] + b4[c].z);
            sv.w = f2bf(acc[3] + b4[c].w);
            *reinterpret_cast<ushort4*>(
                qk + (size_t)(nodeBase + l15) * COLS + colBase + g * 16 + c * 4) = sv;
        }
    }
}

// ---------------------------------------------------------------------------
// K2 (MFMA, r13 exact): block = 128 threads = 2 independent head-pair waves;
// 4 tiles of 16 edges; permuted dwordx4 gathers; in-lane ef; (128,6).
// ---------------------------------------------------------------------------
__global__ __launch_bounds__(128, 6) void edge_attn(
    const float* __restrict__ dist,
    const int* __restrict__ nbrs,      // [E][2]
    const float* __restrict__ Wdk,     // [8][64][20]
    const float* __restrict__ bdk,     // [8][64]
    const unsigned short* __restrict__ qk, // [N][1024] bf16, permuted
    float* __restrict__ out)           // [E][8]
{
    const int tid = threadIdx.x;
    const int hp = (blockIdx.x & 1) * 2 + (tid >> 6);  // head pair 0..3
    const int h0 = hp * 2;
    const int tg = blockIdx.x >> 1;                     // tile group
    const int lane = tid & 63;
    const int l15 = lane & 15;
    const int g = lane >> 4;

    // ---- A-frags: W_dk rows for this head pair (+bias at k=20), once ----
    short8 aw[8];
#pragma unroll
    for (int m = 0; m < 8; ++m) {
        int R = (h0 + (m >> 2)) * 64 + 16 * (m & 3) + l15;
        float wv[8];
        if (g < 2) {
            const float* p = Wdk + R * 20 + 8 * g;
            float4 v0 = *reinterpret_cast<const float4*>(p);
            float4 v1 = *reinterpret_cast<const float4*>(p + 4);
            wv[0]=v0.x; wv[1]=v0.y; wv[2]=v0.z; wv[3]=v0.w;
            wv[4]=v1.x; wv[5]=v1.y; wv[6]=v1.z; wv[7]=v1.w;
        } else if (g == 2) {
            const float* p = Wdk + R * 20 + 16;
            float4 v0 = *reinterpret_cast<const float4*>(p);
            wv[0]=v0.x; wv[1]=v0.y; wv[2]=v0.z; wv[3]=v0.w;
            wv[4]=bdk[R]; wv[5]=0.0f; wv[6]=0.0f; wv[7]=0.0f;
        } else {
            wv[0]=wv[1]=wv[2]=wv[3]=wv[4]=wv[5]=wv[6]=wv[7]=0.0f;
        }
        frag_u f;
        f.i.x = pack2bf(wv[0], wv[1]);
        f.i.y = pack2bf(wv[2], wv[3]);
        f.i.z = pack2bf(wv[4], wv[5]);
        f.i.w = pack2bf(wv[6], wv[7]);
        aw[m] = f.s;
    }

    const char* qkb = reinterpret_cast<const char*>(qk);

#pragma unroll 1
    for (int i = 0; i < 4; ++i) {
        const int tile = tg * 4 + i;
        if (tile >= N_EDGES / 16) break;     // tiles 0..9374
        const int e = tile * 16 + l15;

        // ---- gathers: 8 x dwordx4 (permuted layout, 32B/lane/head) ----
        int2 nn = *reinterpret_cast<const int2*>(&nbrs[2 * e]);
        const char* bq = qkb + (size_t)nn.x * 2048 + h0 * 128 + 32 * g;
        const char* bk = qkb + (size_t)nn.y * 2048 + 1024 + h0 * 128 + 32 * g;
        uint4 qv[4], kv[4];
        qv[0] = *reinterpret_cast<const uint4*>(bq);
        qv[1] = *reinterpret_cast<const uint4*>(bq + 16);
        qv[2] = *reinterpret_cast<const uint4*>(bq + 128);
        qv[3] = *reinterpret_cast<const uint4*>(bq + 144);
        kv[0] = *reinterpret_cast<const uint4*>(bk);
        kv[1] = *reinterpret_cast<const uint4*>(bk + 16);
        kv[2] = *reinterpret_cast<const uint4*>(bk + 128);
        kv[3] = *reinterpret_cast<const uint4*>(bk + 144);

        unsigned int qr[16], kr[16];         // static indices only
#pragma unroll
        for (int j = 0; j < 4; ++j) {
            qr[4*j+0] = qv[j].x; qr[4*j+1] = qv[j].y;
            qr[4*j+2] = qv[j].z; qr[4*j+3] = qv[j].w;
            kr[4*j+0] = kv[j].x; kr[4*j+1] = kv[j].y;
            kr[4*j+2] = kv[j].z; kr[4*j+3] = kv[j].w;
        }

        // ---- ef for this lane's edge (redundant across g, pure VALU) ----
        float ef[N_RBF];
        {
            float d = dist[e];
            float theta = 0.62831853071795864769f * d;   // pi*d/5
            float s1, c1;
            __sincosf(theta, &s1, &c1);
            float env = (d < 5.0f) ? 0.5f * (c1 + 1.0f) : 0.0f;
            float scale = env / d;
            float twoc = 2.0f * c1, sm1 = 0.0f, ss = s1;
#pragma unroll
            for (int r = 0; r < N_RBF; ++r) {
                ef[r] = ss * scale;                      // static indices only
                float nx = twoc * ss - sm1;
                sm1 = ss; ss = nx;
            }
        }

        // select this lane's 8-k slice (k = 8g..8g+7); static ef indices
        frag_u bf_;
        {
            float v[8];
#pragma unroll
            for (int j = 0; j < 8; ++j) {
                float a0 = ef[j];                        // g==0
                float a1 = ef[j + 8];                    // g==1
                float a2 = (j + 16 < 20) ? ef[(j + 16 < 20) ? j + 16 : 0]
                                         : (j + 16 == 20 ? 1.0f : 0.0f); // g==2
                v[j] = (g == 0) ? a0 : (g == 1) ? a1 : (g == 2) ? a2 : 0.0f;
            }
            bf_.i.x = pack2bf(v[0], v[1]);
            bf_.i.y = pack2bf(v[2], v[3]);
            bf_.i.z = pack2bf(v[4], v[5]);
            bf_.i.w = pack2bf(v[6], v[7]);
        }

        // ---- 8 MFMAs + contraction ----
        float tA = 0.0f, tB = 0.0f;
#pragma unroll
        for (int m = 0; m < 8; ++m) {
            f32x4 z = {0.0f, 0.0f, 0.0f, 0.0f};
            f32x4 acc = __builtin_amdgcn_mfma_f32_16x16x32_bf16(aw[m], bf_.s, z, 0, 0, 0);
            const int hh = m >> 2, t = m & 3;
#pragma unroll
            for (int r2 = 0; r2 < 4; ++r2) {
                const int dw = hh * 8 + t * 2 + (r2 >> 1);
                unsigned int qw = qr[dw];
                unsigned int kw = kr[dw];
                float qf = (r2 & 1) ? __uint_as_float(qw & 0xFFFF0000u)
                                    : __uint_as_float(qw << 16);
                float kf = (r2 & 1) ? __uint_as_float(kw & 0xFFFF0000u)
                                    : __uint_as_float(kw << 16);
                float dk = fsilu(acc[r2]);
                float p = qf * kf;
                if (m < 4) tA = fmaf(p, dk, tA);
                else       tB = fmaf(p, dk, tB);
            }
        }

        // reduce across the 4 lanes sharing this edge
        tA += __shfl_xor(tA, 16);
        tA += __shfl_xor(tA, 32);
        tB += __shfl_xor(tB, 16);
        tB += __shfl_xor(tB, 32);

        if (lane < 16) {
            float2 o = make_float2(fsilu(tA), fsilu(tB));
            *reinterpret_cast<float2*>(out + (size_t)e * 8 + h0) = o;
        }
    }
}

extern "C" void kernel_launch(void* const* d_in, const int* in_sizes, int n_in,
                              void* d_out, int out_size, void* d_ws, size_t ws_size,
                              hipStream_t stream) {
    const float* dist = (const float*)d_in[0];
    const int* nbrs   = (const int*)d_in[1];
    const float* x_i  = (const float*)d_in[2];
    const float* W_q  = (const float*)d_in[3];
    const float* b_q  = (const float*)d_in[4];
    const float* W_k  = (const float*)d_in[5];
    const float* b_k  = (const float*)d_in[6];
    const float* W_dk = (const float*)d_in[7];
    const float* b_dk = (const float*)d_in[8];
    float* out = (float*)d_out;

    unsigned short* qkbuf = (unsigned short*)d_ws;  // 20000*1024 bf16 = 41 MB

    dim3 g1(4, (N_NODES / 16 + 7) / 8);   // 4 col-groups x 157 node-chunks
    qk_project_mfma<<<g1, 256, 0, stream>>>(x_i, W_q, b_q, W_k, b_k, qkbuf);

    const int nTiles = N_EDGES / 16;              // 9375
    const int nb = ((nTiles + 3) / 4) * 2;        // 2344 groups x 2 hp-blocks
    edge_attn<<<nb, 128, 0, stream>>>(dist, nbrs, W_dk, b_dk, qkbuf, out);
}